// Round 8
// baseline (277.315 us; speedup 1.0000x reference)
//
#include <hip/hip_runtime.h>
#include <hip/hip_bf16.h>
#include <stdint.h>

using bf16 = __hip_bfloat16;
typedef float v4f __attribute__((ext_vector_type(4)));
typedef short short8 __attribute__((ext_vector_type(8)));
union U8 { uint4 u; bf16 h[8]; short8 s; };

// Shapes (fixed): B=32, L=S=96, D=512, H=8, DH=64, d_ff=9216. M = B*L = 3072.

// ---- async global->LDS 16B (wave-uniform LDS base + lane*16) ---------------
__device__ __forceinline__ void async_cp16(void* l, const void* g) {
  __builtin_amdgcn_global_load_lds(
      (const __attribute__((address_space(1))) void*)(uintptr_t)g,
      (__attribute__((address_space(3))) void*)(uintptr_t)l, 16, 0, 0);
}

// ---- merged transposes: Wo(9216x512)->WoT + Wq/Wk/Wv(512x512)->WT* ---------
__global__ __launch_bounds__(256) void transpose_all(
    const float* __restrict__ Wo, const float* __restrict__ Wq,
    const float* __restrict__ Wk, const float* __restrict__ Wv,
    bf16* __restrict__ WoT, bf16* __restrict__ WTq,
    bf16* __restrict__ WTk, bf16* __restrict__ WTv) {
  __shared__ bf16 T[32][33];
  const int bid = blockIdx.x;
  const float* src; bf16* dst; int K, N, kx, ny;
  if (bid < 4608) {                     // Wo: 288 x 16 tiles
    src = Wo; dst = WoT; K = 9216; N = 512; kx = bid % 288; ny = bid / 288;
  } else {
    const int r = bid - 4608, which = r >> 8, rr = r & 255;
    kx = rr & 15; ny = rr >> 4; K = 512; N = 512;
    src = which == 0 ? Wq : (which == 1 ? Wk : Wv);
    dst = which == 0 ? WTq : (which == 1 ? WTk : WTv);
  }
  const int k0 = kx * 32, n0 = ny * 32;
  const int t = threadIdx.x;
  const int r = t >> 3, c = (t & 7) * 4;
  float4 v = *reinterpret_cast<const float4*>(src + (size_t)(k0 + r) * N + n0 + c);
  T[c + 0][r] = __float2bfloat16(v.x);
  T[c + 1][r] = __float2bfloat16(v.y);
  T[c + 2][r] = __float2bfloat16(v.z);
  T[c + 3][r] = __float2bfloat16(v.w);
  __syncthreads();
  union { uint2 u; bf16 h[4]; } o;
  o.h[0] = T[r][c + 0]; o.h[1] = T[r][c + 1];
  o.h[2] = T[r][c + 2]; o.h[3] = T[r][c + 3];
  *reinterpret_cast<uint2*>(dst + (size_t)(n0 + r) * K + k0 + c) = o.u;
}

// ---- fused Q/K/V projections: LDS-free, barrier-free MFMA ------------------
// z==0 folds core[n,h]/8 into the output (raw-reshape: n=row/384, h=col&63).
// Tile 128m x 64n, 4 waves each own 32 rows x 64 cols. Grid (24, 8, 3).
__global__ __launch_bounds__(256) void proj_mfma(
    const float* __restrict__ X0, const float* __restrict__ X1,
    const float* __restrict__ X2,
    const bf16* __restrict__ WT0, const bf16* __restrict__ WT1,
    const bf16* __restrict__ WT2,
    const float* __restrict__ b0, const float* __restrict__ b1,
    const float* __restrict__ b2, const float* __restrict__ core,
    bf16* __restrict__ O0, bf16* __restrict__ O1, bf16* __restrict__ O2) {
  const int z = blockIdx.z;
  const float* X   = z == 0 ? X0 : (z == 1 ? X1 : X2);
  const bf16* WT   = z == 0 ? WT0 : (z == 1 ? WT1 : WT2);
  const float* bia = z == 0 ? b0 : (z == 1 ? b1 : b2);
  bf16* O          = z == 0 ? O0 : (z == 1 ? O1 : O2);

  const int t = threadIdx.x, w = t >> 6, lane = t & 63;
  const int m16 = lane & 15, q = lane >> 4;
  const int bm = blockIdx.x * 128, bn = blockIdx.y * 64;

  v4f acc[2][4] = {};

  #pragma unroll
  for (int k0 = 0; k0 < 512; k0 += 64) {
    #pragma unroll
    for (int s = 0; s < 2; s++) {
      const int kof = k0 + s * 32 + q * 8;
      short8 af[2], bfr[4];
      #pragma unroll
      for (int mt = 0; mt < 2; mt++) {
        const float* xp = X + (size_t)(bm + w * 32 + mt * 16 + m16) * 512 + kof;
        float4 x0 = reinterpret_cast<const float4*>(xp)[0];
        float4 x1 = reinterpret_cast<const float4*>(xp)[1];
        U8 a;
        a.h[0] = __float2bfloat16(x0.x); a.h[1] = __float2bfloat16(x0.y);
        a.h[2] = __float2bfloat16(x0.z); a.h[3] = __float2bfloat16(x0.w);
        a.h[4] = __float2bfloat16(x1.x); a.h[5] = __float2bfloat16(x1.y);
        a.h[6] = __float2bfloat16(x1.z); a.h[7] = __float2bfloat16(x1.w);
        af[mt] = a.s;
      }
      #pragma unroll
      for (int nt = 0; nt < 4; nt++)
        bfr[nt] = *reinterpret_cast<const short8*>(
            WT + (size_t)(bn + nt * 16 + m16) * 512 + kof);
      #pragma unroll
      for (int mt = 0; mt < 2; mt++)
        #pragma unroll
        for (int nt = 0; nt < 4; nt++)
          acc[mt][nt] = __builtin_amdgcn_mfma_f32_16x16x32_bf16(
              af[mt], bfr[nt], acc[mt][nt], 0, 0, 0);
    }
  }

  const bool isQ = (z == 0);
  const int nblk = bm / 384;                   // block-uniform head index
  #pragma unroll
  for (int mt = 0; mt < 2; mt++)
    #pragma unroll
    for (int nt = 0; nt < 4; nt++)
      #pragma unroll
      for (int r = 0; r < 4; r++) {
        const int row = bm + w * 32 + mt * 16 + q * 4 + r;
        const int col = bn + nt * 16 + m16;
        float v = acc[mt][nt][r] + bia[col];
        if (isQ) v *= core[nblk * 64 + (col & 63)] * 0.125f;
        O[(size_t)row * 512 + col] = __float2bfloat16(v);
      }
}

// ------------- stage B: LDS-free, barrier-free K-loop -----------------------
// full[b,i,j,k'] = sum_n sum_h aq[n,b,i,h]*K[n,b,j,h]*V[n,b,k',h]
// A-frag = bf16(K * aq) built in registers; B-frag = V uint4 direct.
// raw-reshape: P[n*196608 + b*6144 + i*64 + h]. TI=2. Grid (48, 32).
__global__ __launch_bounds__(256) void stage_b_mfma(
    const bf16* __restrict__ AQ, const bf16* __restrict__ KPb,
    const bf16* __restrict__ VPb, bf16* __restrict__ FULL) {
  const int b = blockIdx.y;
  const int i0 = blockIdx.x * 2;

  __shared__ __align__(16) bf16 smem[2 * 9216];   // epilogue staging only

  const int t = threadIdx.x;
  const int w = t >> 6, lane = t & 63;
  const int wr = w >> 1, wc = w & 1;     // 2x2 waves, each 48x48 region
  const int m16 = lane & 15, q = lane >> 4;

  const size_t slab = (size_t)b * 6144;
  v4f acc[2][3][3] = {};

  for (int n = 0; n < 8; n++) {
    const bf16* Kp = KPb + (size_t)n * 196608 + slab;
    const bf16* Vp = VPb + (size_t)n * 196608 + slab;
    const bf16* Ap = AQ + (size_t)n * 196608 + slab + i0 * 64;
    #pragma unroll
    for (int s = 0; s < 2; s++) {
      const int kof = s * 32 + q * 8;
      U8 a0, a1;
      a0.u = *reinterpret_cast<const uint4*>(Ap + kof);
      a1.u = *reinterpret_cast<const uint4*>(Ap + 64 + kof);
      float a0f[8], a1f[8];
      #pragma unroll
      for (int e = 0; e < 8; e++) {
        a0f[e] = __bfloat162float(a0.h[e]);
        a1f[e] = __bfloat162float(a1.h[e]);
      }
      short8 bfr[3], af0[3], af1[3];
      #pragma unroll
      for (int cc = 0; cc < 3; cc++)
        bfr[cc] = *reinterpret_cast<const short8*>(
            Vp + (wc * 48 + cc * 16 + m16) * 64 + kof);
      #pragma unroll
      for (int a = 0; a < 3; a++) {
        U8 kv, s0, s1;
        kv.u = *reinterpret_cast<const uint4*>(
            Kp + (wr * 48 + a * 16 + m16) * 64 + kof);
        #pragma unroll
        for (int e = 0; e < 8; e++) {
          const float kf = __bfloat162float(kv.h[e]);
          s0.h[e] = __float2bfloat16(kf * a0f[e]);
          s1.h[e] = __float2bfloat16(kf * a1f[e]);
        }
        af0[a] = s0.s;
        af1[a] = s1.s;
      }
      #pragma unroll
      for (int a = 0; a < 3; a++)
        #pragma unroll
        for (int cc = 0; cc < 3; cc++) {
          acc[0][a][cc] = __builtin_amdgcn_mfma_f32_16x16x32_bf16(
              af0[a], bfr[cc], acc[0][a][cc], 0, 0, 0);
          acc[1][a][cc] = __builtin_amdgcn_mfma_f32_16x16x32_bf16(
              af1[a], bfr[cc], acc[1][a][cc], 0, 0, 0);
        }
    }
  }

  // epilogue: assemble rows in LDS, coalesced 16B global stores
  #pragma unroll
  for (int isel = 0; isel < 2; isel++)
    #pragma unroll
    for (int a = 0; a < 3; a++)
      #pragma unroll
      for (int cc = 0; cc < 3; cc++) {
        const int j0 = wr * 48 + a * 16, k0c = wc * 48 + cc * 16;
        #pragma unroll
        for (int r = 0; r < 4; r++)
          smem[isel * 9216 + (j0 + q * 4 + r) * 96 + k0c + m16] =
              __float2bfloat16(acc[isel][a][cc][r]);
      }
  __syncthreads();
  const size_t obase = (size_t)(b * 96 + i0) * 9216;
  #pragma unroll
  for (int c = t; c < 2304; c += 256)
    *reinterpret_cast<uint4*>(FULL + obase + c * 8) =
        *reinterpret_cast<const uint4*>(&smem[c * 8]);
}

// ---- init out with bias (d_out is poisoned each launch) --------------------
__global__ __launch_bounds__(256) void init_out(
    const float* __restrict__ bo, float* __restrict__ out) {
  const int idx = (blockIdx.x * 256 + threadIdx.x) * 4;   // < 3072*512
  *reinterpret_cast<float4*>(out + idx) =
      *reinterpret_cast<const float4*>(bo + (idx & 511));
}

// ------- stage C (R6 config: 128x64, BK=128, split-K=4, async swizzled) -----
// LDS rows: 128 bf16 = 256 B, phys chunk = logical chunk ^ (row & 7)
__global__ __launch_bounds__(256) void stage_c_mfma(
    const bf16* __restrict__ FULL, const bf16* __restrict__ WoT,
    float* __restrict__ out) {
  const int bm = blockIdx.x * 128, bn = blockIdx.y * 64;
  const int kbase = blockIdx.z * 2304;
  __shared__ __align__(16) bf16 As[128 * 128];   // 32 KB
  __shared__ __align__(16) bf16 Bs[64 * 128];    // 16 KB
  const int t = threadIdx.x;
  const int w = t >> 6, lane = t & 63;
  const int m16 = lane & 15, q = lane >> 4;
  const int l16 = lane >> 4, l15 = lane & 15;

  v4f acc[2][4] = {};

  for (int k0 = kbase; k0 < kbase + 2304; k0 += 128) {
    __syncthreads();
    #pragma unroll
    for (int c = 0; c < 8; c++) {                // A: 8 calls/wave, 4 rows each
      const int row = (w * 8 + c) * 4 + l16;
      const int lch = l15 ^ (row & 7);
      async_cp16(&As[(w * 8 + c) * 512],
                 FULL + (size_t)(bm + row) * 9216 + k0 + lch * 8);
    }
    #pragma unroll
    for (int c = 0; c < 4; c++) {                // B: 4 calls/wave
      const int row = (w * 4 + c) * 4 + l16;
      const int lch = l15 ^ (row & 7);
      async_cp16(&Bs[(w * 4 + c) * 512],
                 WoT + (size_t)(bn + row) * 9216 + k0 + lch * 8);
    }
    __syncthreads();

    #pragma unroll
    for (int s = 0; s < 4; s++) {
      const int pc = ((s * 4 + q) ^ (m16 & 7)) * 8;
      short8 af[2], bfr[4];
      #pragma unroll
      for (int mt = 0; mt < 2; mt++)
        af[mt] = *reinterpret_cast<const short8*>(
            &As[(w * 32 + mt * 16 + m16) * 128 + pc]);
      #pragma unroll
      for (int nt = 0; nt < 4; nt++)
        bfr[nt] = *reinterpret_cast<const short8*>(
            &Bs[(nt * 16 + m16) * 128 + pc]);
      #pragma unroll
      for (int mt = 0; mt < 2; mt++)
        #pragma unroll
        for (int nt = 0; nt < 4; nt++)
          acc[mt][nt] = __builtin_amdgcn_mfma_f32_16x16x32_bf16(
              af[mt], bfr[nt], acc[mt][nt], 0, 0, 0);
    }
  }

  #pragma unroll
  for (int mt = 0; mt < 2; mt++)
    #pragma unroll
    for (int nt = 0; nt < 4; nt++)
      #pragma unroll
      for (int r = 0; r < 4; r++) {
        const int row = bm + w * 32 + mt * 16 + q * 4 + r;
        const int col = bn + nt * 16 + m16;
        atomicAdd(&out[(size_t)row * 512 + col], acc[mt][nt][r]);
      }
}

extern "C" void kernel_launch(void* const* d_in, const int* in_sizes, int n_in,
                              void* d_out, int out_size, void* d_ws, size_t ws_size,
                              hipStream_t stream) {
  const float* queries = (const float*)d_in[0];
  const float* keys    = (const float*)d_in[1];
  const float* values  = (const float*)d_in[2];
  // d_in[3] = attn_mask (unused by reference)
  const float* Wq   = (const float*)d_in[4];
  const float* bq   = (const float*)d_in[5];
  const float* Wk   = (const float*)d_in[6];
  const float* bk   = (const float*)d_in[7];
  const float* Wv   = (const float*)d_in[8];
  const float* bv   = (const float*)d_in[9];
  const float* core = (const float*)d_in[10];
  const float* Wo   = (const float*)d_in[11];
  const float* bo   = (const float*)d_in[12];
  float* out = (float*)d_out;

  char* ws = (char*)d_ws;
  bf16* AQb = (bf16*)(ws);                   // 3.15 MB (3072*512) = core*q/8
  bf16* KPb = (bf16*)(ws + 3145728);         // 3.15 MB
  bf16* VPb = (bf16*)(ws + 6291456);         // 3.15 MB
  bf16* WTq = (bf16*)(ws + 9437184);         // 0.52 MB (512*512)
  bf16* WTk = (bf16*)(ws + 9961472);         // 0.52 MB
  bf16* WTv = (bf16*)(ws + 10485760);        // 0.52 MB
  bf16* WoT = (bf16*)(ws + 11010048);        // 9.44 MB (512*9216)
  bf16* FULL = (bf16*)(ws + 20447232);       // 56.62 MB (3072*9216)

  const dim3 blk(256);

  transpose_all<<<dim3(5376), blk, 0, stream>>>(
      Wo, Wq, Wk, Wv, WoT, WTq, WTk, WTv);

  proj_mfma<<<dim3(24, 8, 3), blk, 0, stream>>>(
      queries, keys, values, WTq, WTk, WTv, bq, bk, bv, core, AQb, KPb, VPb);

  stage_b_mfma<<<dim3(48, 32), blk, 0, stream>>>(AQb, KPb, VPb, FULL);

  init_out<<<dim3(1536), blk, 0, stream>>>(bo, out);
  stage_c_mfma<<<dim3(24, 8, 4), blk, 0, stream>>>(FULL, WoT, out);
}

// Round 9
// 226.259 us; speedup vs baseline: 1.2257x; 1.2257x over previous
//
#include <hip/hip_runtime.h>
#include <hip/hip_bf16.h>
#include <stdint.h>

using bf16 = __hip_bfloat16;
typedef float v4f __attribute__((ext_vector_type(4)));
typedef short short8 __attribute__((ext_vector_type(8)));

// Shapes (fixed): B=32, L=S=96, D=512, H=8, DH=64, d_ff=9216. M = B*L = 3072.

// ---- async global->LDS 16B (wave-uniform LDS base + lane*16) ---------------
__device__ __forceinline__ void async_cp16(void* l, const void* g) {
  __builtin_amdgcn_global_load_lds(
      (const __attribute__((address_space(1))) void*)(uintptr_t)g,
      (__attribute__((address_space(3))) void*)(uintptr_t)l, 16, 0, 0);
}

// ---- transpose + f32->bf16: Wo (9216x512) f32 -> WoT (512x9216) bf16 -------
__global__ __launch_bounds__(256) void transpose_wo(
    const float* __restrict__ src, bf16* __restrict__ dst) {
  __shared__ bf16 T[32][33];
  const int k0 = blockIdx.x * 32, n0 = blockIdx.y * 32;
  const int t = threadIdx.x;
  const int r = t >> 3, c = (t & 7) * 4;
  float4 v = *reinterpret_cast<const float4*>(src + (size_t)(k0 + r) * 512 + n0 + c);
  T[c + 0][r] = __float2bfloat16(v.x);
  T[c + 1][r] = __float2bfloat16(v.y);
  T[c + 2][r] = __float2bfloat16(v.z);
  T[c + 3][r] = __float2bfloat16(v.w);
  __syncthreads();
  union { uint2 u; bf16 h[4]; } o;
  o.h[0] = T[r][c + 0]; o.h[1] = T[r][c + 1];
  o.h[2] = T[r][c + 2]; o.h[3] = T[r][c + 3];
  *reinterpret_cast<uint2*>(dst + (size_t)(n0 + r) * 9216 + k0 + c) = o.u;
}

// ---- fused Q/K/V projections (MFMA), W transposed in-staging (R7 version) --
// z==0 folds core[n,h]/8 into the output (raw-reshape: n=row/384, h=col&63).
#define PJ_LD 72

__global__ __launch_bounds__(256) void proj_mfma(
    const float* __restrict__ X0, const float* __restrict__ X1,
    const float* __restrict__ X2,
    const float* __restrict__ W0, const float* __restrict__ W1,
    const float* __restrict__ W2,
    const float* __restrict__ b0, const float* __restrict__ b1,
    const float* __restrict__ b2, const float* __restrict__ core,
    bf16* __restrict__ O0, bf16* __restrict__ O1, bf16* __restrict__ O2) {
  const int z = blockIdx.z;
  const float* X   = z == 0 ? X0 : (z == 1 ? X1 : X2);
  const float* W   = z == 0 ? W0 : (z == 1 ? W1 : W2);
  const float* bia = z == 0 ? b0 : (z == 1 ? b1 : b2);
  bf16* O          = z == 0 ? O0 : (z == 1 ? O1 : O2);

  __shared__ __align__(16) bf16 As[64 * PJ_LD];
  __shared__ __align__(16) bf16 Bs[64 * PJ_LD];   // Bs[n][k]
  const int t = threadIdx.x, w = t >> 6, lane = t & 63;
  const int wr = w >> 1, wc = w & 1, m16 = lane & 15, q = lane >> 4;
  const int bm = blockIdx.x * 64, bn = blockIdx.y * 64;

  v4f acc[2][2] = {};

  for (int k0 = 0; k0 < 512; k0 += 64) {
    __syncthreads();
    #pragma unroll
    for (int c = t; c < 1024; c += 256) {     // A: 64x64 f32 -> bf16
      const int row = c >> 4, col = (c & 15) * 4;
      float4 v = *reinterpret_cast<const float4*>(
          X + (size_t)(bm + row) * 512 + k0 + col);
      union { uint2 u; bf16 h[4]; } o;
      o.h[0] = __float2bfloat16(v.x); o.h[1] = __float2bfloat16(v.y);
      o.h[2] = __float2bfloat16(v.z); o.h[3] = __float2bfloat16(v.w);
      *reinterpret_cast<uint2*>(&As[row * PJ_LD + col]) = o.u;
    }
    #pragma unroll
    for (int c = t; c < 1024; c += 256) {     // B: W[k][n] f32 -> Bs[n][k] bf16
      const int kr = c >> 4, nc = (c & 15) * 4;
      float4 v = *reinterpret_cast<const float4*>(
          W + (size_t)(k0 + kr) * 512 + bn + nc);
      Bs[(nc + 0) * PJ_LD + kr] = __float2bfloat16(v.x);
      Bs[(nc + 1) * PJ_LD + kr] = __float2bfloat16(v.y);
      Bs[(nc + 2) * PJ_LD + kr] = __float2bfloat16(v.z);
      Bs[(nc + 3) * PJ_LD + kr] = __float2bfloat16(v.w);
    }
    __syncthreads();

    #pragma unroll
    for (int s = 0; s < 2; s++) {
      const int koff = s * 32 + q * 8;
      short8 af[2], bfr[2];
      #pragma unroll
      for (int mt = 0; mt < 2; mt++)
        af[mt] = *reinterpret_cast<const short8*>(
            &As[(wr * 32 + mt * 16 + m16) * PJ_LD + koff]);
      #pragma unroll
      for (int nt = 0; nt < 2; nt++)
        bfr[nt] = *reinterpret_cast<const short8*>(
            &Bs[(wc * 32 + nt * 16 + m16) * PJ_LD + koff]);
      #pragma unroll
      for (int mt = 0; mt < 2; mt++)
        #pragma unroll
        for (int nt = 0; nt < 2; nt++)
          acc[mt][nt] = __builtin_amdgcn_mfma_f32_16x16x32_bf16(
              af[mt], bfr[nt], acc[mt][nt], 0, 0, 0);
    }
  }

  const bool isQ = (z == 0);
  const int nblk = bm / 384;                   // wave-uniform head index
  #pragma unroll
  for (int mt = 0; mt < 2; mt++)
    #pragma unroll
    for (int nt = 0; nt < 2; nt++)
      #pragma unroll
      for (int r = 0; r < 4; r++) {
        const int row = bm + wr * 32 + mt * 16 + q * 4 + r;
        const int col = bn + wc * 32 + nt * 16 + m16;
        float v = acc[mt][nt][r] + bia[col];
        if (isQ) v *= core[nblk * 64 + (col & 63)] * 0.125f;
        O[(size_t)row * 512 + col] = __float2bfloat16(v);
      }
}

// ------------- stage B (R6 version: MFMA, TI=2, async V, swizzled LDS) ------
// raw-reshape indexing: aq/k/v[n,b,i,h] = P[n*196608 + b*6144 + i*64 + h]
// LDS rows: 64 bf16 = 128 B, phys chunk = logical chunk ^ (row & 7)
__global__ __launch_bounds__(256) void stage_b_mfma(
    const bf16* __restrict__ AQ, const bf16* __restrict__ KPb,
    const bf16* __restrict__ VPb, bf16* __restrict__ FULL) {
  const int b = blockIdx.y;
  const int i0 = blockIdx.x * 2;

  __shared__ __align__(16) bf16 smem[19456];  // Ks0|Ks1|Vs|aq2 ; epi: 2x9216
  bf16* Ks0 = smem;            // 6144 (96x64 swizzled)
  bf16* Ks1 = smem + 6144;
  bf16* Vs  = smem + 12288;
  bf16* aqs = smem + 18432;    // 2 x 512

  const int t = threadIdx.x;
  const int w = t >> 6, lane = t & 63;
  const int wr = w >> 1, wc = w & 1;    // 2x2 waves, each 48x48 region
  const int m16 = lane & 15, q = lane >> 4;
  const int l8 = lane >> 3, l7 = lane & 7;

  if (t < 128) {                         // load aq rows for both i
    const int isel = t & 1, n = t >> 4, seg = (t >> 1) & 7;
    *reinterpret_cast<uint4*>(&aqs[isel * 512 + n * 64 + seg * 8]) =
        *reinterpret_cast<const uint4*>(
            AQ + (size_t)n * 196608 + b * 6144 + (i0 + isel) * 64 + seg * 8);
  }

  union U8 { uint4 u; bf16 h[8]; };
  const int colq = (t & 7) * 8;          // k-column of this thread's K chunks
  const int rowk = t >> 3;               // base K row (+32 per chunk iter)
  const int krow7 = rowk & 7;

  U8 kk[3];
  {
    const bf16* Kp = KPb + b * 6144;     // n = 0 slab
    #pragma unroll
    for (int c3 = 0; c3 < 3; c3++)
      kk[c3].u = *reinterpret_cast<const uint4*>(Kp + (t + c3 * 256) * 8);
  }

  v4f acc[2][3][3] = {};

  for (int n = 0; n < 8; n++) {
    __syncthreads();                     // prev frag reads done; aqs ready
    // async V staging (swizzled): 3 calls/wave, 8 rows each
    const bf16* Vp = VPb + (size_t)n * 196608 + b * 6144;
    #pragma unroll
    for (int c = 0; c < 3; c++) {
      const int r0 = (w * 3 + c) * 8;
      async_cp16(&Vs[(w * 3 + c) * 512],
                 Vp + (r0 + l8) * 64 + (l7 ^ l8) * 8);
    }
    // aq scales for this n (f32, hoisted)
    float a0f[8], a1f[8];
    {
      U8 a0, a1;
      a0.u = *reinterpret_cast<const uint4*>(&aqs[n * 64 + colq]);
      a1.u = *reinterpret_cast<const uint4*>(&aqs[512 + n * 64 + colq]);
      #pragma unroll
      for (int e = 0; e < 8; e++) {
        a0f[e] = __bfloat162float(a0.h[e]);
        a1f[e] = __bfloat162float(a1.h[e]);
      }
    }
    // repack K with per-i scales into swizzled LDS
    #pragma unroll
    for (int c3 = 0; c3 < 3; c3++) {
      U8 s0, s1;
      #pragma unroll
      for (int e = 0; e < 8; e++) {
        const float kv = __bfloat162float(kk[c3].h[e]);
        s0.h[e] = __float2bfloat16(kv * a0f[e]);
        s1.h[e] = __float2bfloat16(kv * a1f[e]);
      }
      const int phys = (rowk + 32 * c3) * 64 + (l7 ^ krow7) * 8;
      *reinterpret_cast<uint4*>(&Ks0[phys]) = s0.u;
      *reinterpret_cast<uint4*>(&Ks1[phys]) = s1.u;
    }
    __syncthreads();                     // drains async V + K writes
    // prefetch next n's K slab (latency hides behind MFMAs)
    if (n < 7) {
      const bf16* Kp1 = KPb + (size_t)(n + 1) * 196608 + b * 6144;
      #pragma unroll
      for (int c3 = 0; c3 < 3; c3++)
        kk[c3].u = *reinterpret_cast<const uint4*>(Kp1 + (t + c3 * 256) * 8);
    }

    #pragma unroll
    for (int s = 0; s < 2; s++) {
      const int pc = ((s * 4 + q) ^ (m16 & 7)) * 8;
      short8 bfr[3], af0[3], af1[3];
      #pragma unroll
      for (int cc = 0; cc < 3; cc++)
        bfr[cc] = *reinterpret_cast<const short8*>(
            &Vs[(wc * 48 + cc * 16 + m16) * 64 + pc]);
      #pragma unroll
      for (int a = 0; a < 3; a++) {
        af0[a] = *reinterpret_cast<const short8*>(
            &Ks0[(wr * 48 + a * 16 + m16) * 64 + pc]);
        af1[a] = *reinterpret_cast<const short8*>(
            &Ks1[(wr * 48 + a * 16 + m16) * 64 + pc]);
      }
      #pragma unroll
      for (int a = 0; a < 3; a++)
        #pragma unroll
        for (int cc = 0; cc < 3; cc++) {
          acc[0][a][cc] = __builtin_amdgcn_mfma_f32_16x16x32_bf16(
              af0[a], bfr[cc], acc[0][a][cc], 0, 0, 0);
          acc[1][a][cc] = __builtin_amdgcn_mfma_f32_16x16x32_bf16(
              af1[a], bfr[cc], acc[1][a][cc], 0, 0, 0);
        }
    }
  }

  // epilogue: assemble rows in LDS, then coalesced 16B global stores
  __syncthreads();
  #pragma unroll
  for (int isel = 0; isel < 2; isel++)
    #pragma unroll
    for (int a = 0; a < 3; a++)
      #pragma unroll
      for (int cc = 0; cc < 3; cc++) {
        const int j0 = wr * 48 + a * 16, k0c = wc * 48 + cc * 16;
        #pragma unroll
        for (int r = 0; r < 4; r++)
          smem[isel * 9216 + (j0 + q * 4 + r) * 96 + k0c + m16] =
              __float2bfloat16(acc[isel][a][cc][r]);
      }
  __syncthreads();
  const size_t obase = (size_t)(b * 96 + i0) * 9216;
  #pragma unroll
  for (int c = t; c < 2304; c += 256)
    *reinterpret_cast<uint4*>(FULL + obase + c * 8) =
        *reinterpret_cast<const uint4*>(&smem[c * 8]);
}

// ---- init out with bias (d_out is poisoned each launch) --------------------
__global__ __launch_bounds__(256) void init_out(
    const float* __restrict__ bo, float* __restrict__ out) {
  const int idx = (blockIdx.x * 256 + threadIdx.x) * 4;   // < 3072*512
  *reinterpret_cast<float4*>(out + idx) =
      *reinterpret_cast<const float4*>(bo + (idx & 511));
}

// ------- stage C (R6 config: 128x64, BK=128, split-K=4, async swizzled) -----
// LDS rows: 128 bf16 = 256 B, phys chunk = logical chunk ^ (row & 7)
__global__ __launch_bounds__(256) void stage_c_mfma(
    const bf16* __restrict__ FULL, const bf16* __restrict__ WoT,
    float* __restrict__ out) {
  const int bm = blockIdx.x * 128, bn = blockIdx.y * 64;
  const int kbase = blockIdx.z * 2304;
  __shared__ __align__(16) bf16 As[128 * 128];   // 32 KB
  __shared__ __align__(16) bf16 Bs[64 * 128];    // 16 KB
  const int t = threadIdx.x;
  const int w = t >> 6, lane = t & 63;
  const int m16 = lane & 15, q = lane >> 4;
  const int l16 = lane >> 4, l15 = lane & 15;

  v4f acc[2][4] = {};

  for (int k0 = kbase; k0 < kbase + 2304; k0 += 128) {
    __syncthreads();
    #pragma unroll
    for (int c = 0; c < 8; c++) {                // A: 8 calls/wave, 4 rows each
      const int row = (w * 8 + c) * 4 + l16;
      const int lch = l15 ^ (row & 7);
      async_cp16(&As[(w * 8 + c) * 512],
                 FULL + (size_t)(bm + row) * 9216 + k0 + lch * 8);
    }
    #pragma unroll
    for (int c = 0; c < 4; c++) {                // B: 4 calls/wave
      const int row = (w * 4 + c) * 4 + l16;
      const int lch = l15 ^ (row & 7);
      async_cp16(&Bs[(w * 4 + c) * 512],
                 WoT + (size_t)(bn + row) * 9216 + k0 + lch * 8);
    }
    __syncthreads();

    #pragma unroll
    for (int s = 0; s < 4; s++) {
      const int pc = ((s * 4 + q) ^ (m16 & 7)) * 8;
      short8 af[2], bfr[4];
      #pragma unroll
      for (int mt = 0; mt < 2; mt++)
        af[mt] = *reinterpret_cast<const short8*>(
            &As[(w * 32 + mt * 16 + m16) * 128 + pc]);
      #pragma unroll
      for (int nt = 0; nt < 4; nt++)
        bfr[nt] = *reinterpret_cast<const short8*>(
            &Bs[(nt * 16 + m16) * 128 + pc]);
      #pragma unroll
      for (int mt = 0; mt < 2; mt++)
        #pragma unroll
        for (int nt = 0; nt < 4; nt++)
          acc[mt][nt] = __builtin_amdgcn_mfma_f32_16x16x32_bf16(
              af[mt], bfr[nt], acc[mt][nt], 0, 0, 0);
    }
  }

  #pragma unroll
  for (int mt = 0; mt < 2; mt++)
    #pragma unroll
    for (int nt = 0; nt < 4; nt++)
      #pragma unroll
      for (int r = 0; r < 4; r++) {
        const int row = bm + w * 32 + mt * 16 + q * 4 + r;
        const int col = bn + nt * 16 + m16;
        atomicAdd(&out[(size_t)row * 512 + col], acc[mt][nt][r]);
      }
}

extern "C" void kernel_launch(void* const* d_in, const int* in_sizes, int n_in,
                              void* d_out, int out_size, void* d_ws, size_t ws_size,
                              hipStream_t stream) {
  const float* queries = (const float*)d_in[0];
  const float* keys    = (const float*)d_in[1];
  const float* values  = (const float*)d_in[2];
  // d_in[3] = attn_mask (unused by reference)
  const float* Wq   = (const float*)d_in[4];
  const float* bq   = (const float*)d_in[5];
  const float* Wk   = (const float*)d_in[6];
  const float* bk   = (const float*)d_in[7];
  const float* Wv   = (const float*)d_in[8];
  const float* bv   = (const float*)d_in[9];
  const float* core = (const float*)d_in[10];
  const float* Wo   = (const float*)d_in[11];
  const float* bo   = (const float*)d_in[12];
  float* out = (float*)d_out;

  char* ws = (char*)d_ws;
  bf16* AQb = (bf16*)(ws);                   // 3.15 MB (3072*512) = core*q/8
  bf16* KPb = (bf16*)(ws + 3145728);         // 3.15 MB
  bf16* VPb = (bf16*)(ws + 6291456);         // 3.15 MB
  bf16* WoT = (bf16*)(ws + 9437184);         // 9.44 MB (512*9216)
  bf16* FULL = (bf16*)(ws + 18874368);       // 56.62 MB (3072*9216)

  const dim3 blk(256);

  transpose_wo<<<dim3(288, 16), blk, 0, stream>>>(Wo, WoT);

  proj_mfma<<<dim3(48, 8, 3), blk, 0, stream>>>(
      queries, keys, values, Wq, Wk, Wv, bq, bk, bv, core, AQb, KPb, VPb);

  stage_b_mfma<<<dim3(48, 32), blk, 0, stream>>>(AQb, KPb, VPb, FULL);

  init_out<<<dim3(1536), blk, 0, stream>>>(bo, out);
  stage_c_mfma<<<dim3(24, 8, 4), blk, 0, stream>>>(FULL, WoT, out);
}

// Round 10
// 205.362 us; speedup vs baseline: 1.3504x; 1.1018x over previous
//
#include <hip/hip_runtime.h>
#include <hip/hip_bf16.h>
#include <stdint.h>

using bf16 = __hip_bfloat16;
typedef float v4f __attribute__((ext_vector_type(4)));
typedef short short8 __attribute__((ext_vector_type(8)));

// Shapes (fixed): B=32, L=S=96, D=512, H=8, DH=64, d_ff=9216. M = B*L = 3072.

// ---- async global->LDS 16B (wave-uniform LDS base + lane*16) ---------------
__device__ __forceinline__ void async_cp16(void* l, const void* g) {
  __builtin_amdgcn_global_load_lds(
      (const __attribute__((address_space(1))) void*)(uintptr_t)g,
      (__attribute__((address_space(3))) void*)(uintptr_t)l, 16, 0, 0);
}

// ---- prep: all transposes + X f32->bf16 + out bias-init, one launch --------
// blocks: [0,4608) Wo tiles; [4608,5376) Wq/Wk/Wv tiles;
//         [5376,6528) X convert; [6528,8064) init out.
__global__ __launch_bounds__(256) void prep(
    const float* __restrict__ Wo, const float* __restrict__ Wq,
    const float* __restrict__ Wk, const float* __restrict__ Wv,
    const float* __restrict__ Xq, const float* __restrict__ Xk,
    const float* __restrict__ Xv, const float* __restrict__ bo,
    bf16* __restrict__ WoT, bf16* __restrict__ WTq,
    bf16* __restrict__ WTk, bf16* __restrict__ WTv,
    bf16* __restrict__ Xbq, bf16* __restrict__ Xbk, bf16* __restrict__ Xbv,
    float* __restrict__ out) {
  const int bid = blockIdx.x, t = threadIdx.x;
  if (bid < 5376) {                       // transpose f32 -> bf16
    __shared__ bf16 T[32][33];
    const float* src; bf16* dst; int K, N, kx, ny;
    if (bid < 4608) {                     // Wo: 288 x 16 tiles
      src = Wo; dst = WoT; K = 9216; N = 512; kx = bid % 288; ny = bid / 288;
    } else {
      const int r = bid - 4608, which = r >> 8, rr = r & 255;
      kx = rr & 15; ny = rr >> 4; K = 512; N = 512;
      src = which == 0 ? Wq : (which == 1 ? Wk : Wv);
      dst = which == 0 ? WTq : (which == 1 ? WTk : WTv);
    }
    const int k0 = kx * 32, n0 = ny * 32;
    const int r = t >> 3, c = (t & 7) * 4;
    float4 v = *reinterpret_cast<const float4*>(src + (size_t)(k0 + r) * N + n0 + c);
    T[c + 0][r] = __float2bfloat16(v.x);
    T[c + 1][r] = __float2bfloat16(v.y);
    T[c + 2][r] = __float2bfloat16(v.z);
    T[c + 3][r] = __float2bfloat16(v.w);
    __syncthreads();
    union { uint2 u; bf16 h[4]; } o;
    o.h[0] = T[r][c + 0]; o.h[1] = T[r][c + 1];
    o.h[2] = T[r][c + 2]; o.h[3] = T[r][c + 3];
    *reinterpret_cast<uint2*>(dst + (size_t)(n0 + r) * K + k0 + c) = o.u;
  } else if (bid < 6528) {                // X f32 -> bf16 (16 elems/thread)
    const int r = bid - 5376;
    const int which = r / 384, blk = r % 384;
    const float* src = which == 0 ? Xq : (which == 1 ? Xk : Xv);
    bf16* dst = which == 0 ? Xbq : (which == 1 ? Xbk : Xbv);
    const int base = blk * 4096 + t * 16;
    float4 a = *reinterpret_cast<const float4*>(src + base);
    float4 b = *reinterpret_cast<const float4*>(src + base + 4);
    float4 c = *reinterpret_cast<const float4*>(src + base + 8);
    float4 d = *reinterpret_cast<const float4*>(src + base + 12);
    union { uint4 u; bf16 h[8]; } o1, o2;
    o1.h[0] = __float2bfloat16(a.x); o1.h[1] = __float2bfloat16(a.y);
    o1.h[2] = __float2bfloat16(a.z); o1.h[3] = __float2bfloat16(a.w);
    o1.h[4] = __float2bfloat16(b.x); o1.h[5] = __float2bfloat16(b.y);
    o1.h[6] = __float2bfloat16(b.z); o1.h[7] = __float2bfloat16(b.w);
    o2.h[0] = __float2bfloat16(c.x); o2.h[1] = __float2bfloat16(c.y);
    o2.h[2] = __float2bfloat16(c.z); o2.h[3] = __float2bfloat16(c.w);
    o2.h[4] = __float2bfloat16(d.x); o2.h[5] = __float2bfloat16(d.y);
    o2.h[6] = __float2bfloat16(d.z); o2.h[7] = __float2bfloat16(d.w);
    *reinterpret_cast<uint4*>(dst + base) = o1.u;
    *reinterpret_cast<uint4*>(dst + base + 8) = o2.u;
  } else {                                // init out with bias
    const int r = bid - 6528;
    const int idx = (r * 256 + t) * 4;    // < 3072*512
    *reinterpret_cast<float4*>(out + idx) =
        *reinterpret_cast<const float4*>(bo + (idx & 511));
  }
}

// ---- fused Q/K/V projections: stage_c-style 128x64, BK=128, async swizzled -
// z==0 folds core[n,h]/8 into the output (raw-reshape: n=row/384, h=col&63).
// LDS rows: 128 bf16 = 256 B, phys chunk = logical chunk ^ (row & 7)
__global__ __launch_bounds__(256) void proj_mfma(
    const bf16* __restrict__ Xb0, const bf16* __restrict__ Xb1,
    const bf16* __restrict__ Xb2,
    const bf16* __restrict__ WT0, const bf16* __restrict__ WT1,
    const bf16* __restrict__ WT2,
    const float* __restrict__ b0, const float* __restrict__ b1,
    const float* __restrict__ b2, const float* __restrict__ core,
    bf16* __restrict__ O0, bf16* __restrict__ O1, bf16* __restrict__ O2) {
  const int z = blockIdx.z;
  const bf16* X    = z == 0 ? Xb0 : (z == 1 ? Xb1 : Xb2);
  const bf16* WT   = z == 0 ? WT0 : (z == 1 ? WT1 : WT2);
  const float* bia = z == 0 ? b0 : (z == 1 ? b1 : b2);
  bf16* O          = z == 0 ? O0 : (z == 1 ? O1 : O2);

  const int bm = blockIdx.x * 128, bn = blockIdx.y * 64;
  __shared__ __align__(16) bf16 As[128 * 128];   // 32 KB
  __shared__ __align__(16) bf16 Bs[64 * 128];    // 16 KB
  const int t = threadIdx.x;
  const int w = t >> 6, lane = t & 63;
  const int m16 = lane & 15, q = lane >> 4;
  const int l16 = lane >> 4, l15 = lane & 15;

  v4f acc[2][4] = {};

  for (int k0 = 0; k0 < 512; k0 += 128) {
    __syncthreads();
    #pragma unroll
    for (int c = 0; c < 8; c++) {                // A: 8 calls/wave, 4 rows each
      const int row = (w * 8 + c) * 4 + l16;
      const int lch = l15 ^ (row & 7);
      async_cp16(&As[(w * 8 + c) * 512],
                 X + (size_t)(bm + row) * 512 + k0 + lch * 8);
    }
    #pragma unroll
    for (int c = 0; c < 4; c++) {                // B: 4 calls/wave
      const int row = (w * 4 + c) * 4 + l16;
      const int lch = l15 ^ (row & 7);
      async_cp16(&Bs[(w * 4 + c) * 512],
                 WT + (size_t)(bn + row) * 512 + k0 + lch * 8);
    }
    __syncthreads();

    #pragma unroll
    for (int s = 0; s < 4; s++) {
      const int pc = ((s * 4 + q) ^ (m16 & 7)) * 8;
      short8 af[2], bfr[4];
      #pragma unroll
      for (int mt = 0; mt < 2; mt++)
        af[mt] = *reinterpret_cast<const short8*>(
            &As[(w * 32 + mt * 16 + m16) * 128 + pc]);
      #pragma unroll
      for (int nt = 0; nt < 4; nt++)
        bfr[nt] = *reinterpret_cast<const short8*>(
            &Bs[(nt * 16 + m16) * 128 + pc]);
      #pragma unroll
      for (int mt = 0; mt < 2; mt++)
        #pragma unroll
        for (int nt = 0; nt < 4; nt++)
          acc[mt][nt] = __builtin_amdgcn_mfma_f32_16x16x32_bf16(
              af[mt], bfr[nt], acc[mt][nt], 0, 0, 0);
    }
  }

  const bool isQ = (z == 0);
  const int nblk = bm / 384;   // 128 | 384 so head index is tile-uniform
  #pragma unroll
  for (int mt = 0; mt < 2; mt++)
    #pragma unroll
    for (int nt = 0; nt < 4; nt++)
      #pragma unroll
      for (int r = 0; r < 4; r++) {
        const int row = bm + w * 32 + mt * 16 + q * 4 + r;
        const int col = bn + nt * 16 + m16;
        float v = acc[mt][nt][r] + bia[col];
        if (isQ) v *= core[nblk * 64 + (col & 63)] * 0.125f;
        O[(size_t)row * 512 + col] = __float2bfloat16(v);
      }
}

// ------------- stage B (R6/R9 proven: MFMA, TI=2, async V, swizzled LDS) ----
// raw-reshape indexing: aq/k/v[n,b,i,h] = P[n*196608 + b*6144 + i*64 + h]
// LDS rows: 64 bf16 = 128 B, phys chunk = logical chunk ^ (row & 7)
__global__ __launch_bounds__(256) void stage_b_mfma(
    const bf16* __restrict__ AQ, const bf16* __restrict__ KPb,
    const bf16* __restrict__ VPb, bf16* __restrict__ FULL) {
  const int b = blockIdx.y;
  const int i0 = blockIdx.x * 2;

  __shared__ __align__(16) bf16 smem[19456];  // Ks0|Ks1|Vs|aq2 ; epi: 2x9216
  bf16* Ks0 = smem;            // 6144 (96x64 swizzled)
  bf16* Ks1 = smem + 6144;
  bf16* Vs  = smem + 12288;
  bf16* aqs = smem + 18432;    // 2 x 512

  const int t = threadIdx.x;
  const int w = t >> 6, lane = t & 63;
  const int wr = w >> 1, wc = w & 1;    // 2x2 waves, each 48x48 region
  const int m16 = lane & 15, q = lane >> 4;
  const int l8 = lane >> 3, l7 = lane & 7;

  if (t < 128) {                         // load aq rows for both i
    const int isel = t & 1, n = t >> 4, seg = (t >> 1) & 7;
    *reinterpret_cast<uint4*>(&aqs[isel * 512 + n * 64 + seg * 8]) =
        *reinterpret_cast<const uint4*>(
            AQ + (size_t)n * 196608 + b * 6144 + (i0 + isel) * 64 + seg * 8);
  }

  union U8 { uint4 u; bf16 h[8]; };
  const int colq = (t & 7) * 8;          // k-column of this thread's K chunks
  const int rowk = t >> 3;               // base K row (+32 per chunk iter)
  const int krow7 = rowk & 7;

  U8 kk[3];
  {
    const bf16* Kp = KPb + b * 6144;     // n = 0 slab
    #pragma unroll
    for (int c3 = 0; c3 < 3; c3++)
      kk[c3].u = *reinterpret_cast<const uint4*>(Kp + (t + c3 * 256) * 8);
  }

  v4f acc[2][3][3] = {};

  for (int n = 0; n < 8; n++) {
    __syncthreads();                     // prev frag reads done; aqs ready
    // async V staging (swizzled): 3 calls/wave, 8 rows each
    const bf16* Vp = VPb + (size_t)n * 196608 + b * 6144;
    #pragma unroll
    for (int c = 0; c < 3; c++) {
      const int r0 = (w * 3 + c) * 8;
      async_cp16(&Vs[(w * 3 + c) * 512],
                 Vp + (r0 + l8) * 64 + (l7 ^ l8) * 8);
    }
    // aq scales for this n (f32, hoisted)
    float a0f[8], a1f[8];
    {
      U8 a0, a1;
      a0.u = *reinterpret_cast<const uint4*>(&aqs[n * 64 + colq]);
      a1.u = *reinterpret_cast<const uint4*>(&aqs[512 + n * 64 + colq]);
      #pragma unroll
      for (int e = 0; e < 8; e++) {
        a0f[e] = __bfloat162float(a0.h[e]);
        a1f[e] = __bfloat162float(a1.h[e]);
      }
    }
    // repack K with per-i scales into swizzled LDS
    #pragma unroll
    for (int c3 = 0; c3 < 3; c3++) {
      U8 s0, s1;
      #pragma unroll
      for (int e = 0; e < 8; e++) {
        const float kv = __bfloat162float(kk[c3].h[e]);
        s0.h[e] = __float2bfloat16(kv * a0f[e]);
        s1.h[e] = __float2bfloat16(kv * a1f[e]);
      }
      const int phys = (rowk + 32 * c3) * 64 + (l7 ^ krow7) * 8;
      *reinterpret_cast<uint4*>(&Ks0[phys]) = s0.u;
      *reinterpret_cast<uint4*>(&Ks1[phys]) = s1.u;
    }
    __syncthreads();                     // drains async V + K writes
    // prefetch next n's K slab (latency hides behind MFMAs)
    if (n < 7) {
      const bf16* Kp1 = KPb + (size_t)(n + 1) * 196608 + b * 6144;
      #pragma unroll
      for (int c3 = 0; c3 < 3; c3++)
        kk[c3].u = *reinterpret_cast<const uint4*>(Kp1 + (t + c3 * 256) * 8);
    }

    #pragma unroll
    for (int s = 0; s < 2; s++) {
      const int pc = ((s * 4 + q) ^ (m16 & 7)) * 8;
      short8 bfr[3], af0[3], af1[3];
      #pragma unroll
      for (int cc = 0; cc < 3; cc++)
        bfr[cc] = *reinterpret_cast<const short8*>(
            &Vs[(wc * 48 + cc * 16 + m16) * 64 + pc]);
      #pragma unroll
      for (int a = 0; a < 3; a++) {
        af0[a] = *reinterpret_cast<const short8*>(
            &Ks0[(wr * 48 + a * 16 + m16) * 64 + pc]);
        af1[a] = *reinterpret_cast<const short8*>(
            &Ks1[(wr * 48 + a * 16 + m16) * 64 + pc]);
      }
      #pragma unroll
      for (int a = 0; a < 3; a++)
        #pragma unroll
        for (int cc = 0; cc < 3; cc++) {
          acc[0][a][cc] = __builtin_amdgcn_mfma_f32_16x16x32_bf16(
              af0[a], bfr[cc], acc[0][a][cc], 0, 0, 0);
          acc[1][a][cc] = __builtin_amdgcn_mfma_f32_16x16x32_bf16(
              af1[a], bfr[cc], acc[1][a][cc], 0, 0, 0);
        }
    }
  }

  // epilogue: assemble rows in LDS, then coalesced 16B global stores
  __syncthreads();
  #pragma unroll
  for (int isel = 0; isel < 2; isel++)
    #pragma unroll
    for (int a = 0; a < 3; a++)
      #pragma unroll
      for (int cc = 0; cc < 3; cc++) {
        const int j0 = wr * 48 + a * 16, k0c = wc * 48 + cc * 16;
        #pragma unroll
        for (int r = 0; r < 4; r++)
          smem[isel * 9216 + (j0 + q * 4 + r) * 96 + k0c + m16] =
              __float2bfloat16(acc[isel][a][cc][r]);
      }
  __syncthreads();
  const size_t obase = (size_t)(b * 96 + i0) * 9216;
  #pragma unroll
  for (int c = t; c < 2304; c += 256)
    *reinterpret_cast<uint4*>(FULL + obase + c * 8) =
        *reinterpret_cast<const uint4*>(&smem[c * 8]);
}

// ------- stage C (R6/R9 proven: 128x64, BK=128, split-K=4, async swizzled) --
// LDS rows: 128 bf16 = 256 B, phys chunk = logical chunk ^ (row & 7)
__global__ __launch_bounds__(256) void stage_c_mfma(
    const bf16* __restrict__ FULL, const bf16* __restrict__ WoT,
    float* __restrict__ out) {
  const int bm = blockIdx.x * 128, bn = blockIdx.y * 64;
  const int kbase = blockIdx.z * 2304;
  __shared__ __align__(16) bf16 As[128 * 128];   // 32 KB
  __shared__ __align__(16) bf16 Bs[64 * 128];    // 16 KB
  const int t = threadIdx.x;
  const int w = t >> 6, lane = t & 63;
  const int m16 = lane & 15, q = lane >> 4;
  const int l16 = lane >> 4, l15 = lane & 15;

  v4f acc[2][4] = {};

  for (int k0 = kbase; k0 < kbase + 2304; k0 += 128) {
    __syncthreads();
    #pragma unroll
    for (int c = 0; c < 8; c++) {                // A: 8 calls/wave, 4 rows each
      const int row = (w * 8 + c) * 4 + l16;
      const int lch = l15 ^ (row & 7);
      async_cp16(&As[(w * 8 + c) * 512],
                 FULL + (size_t)(bm + row) * 9216 + k0 + lch * 8);
    }
    #pragma unroll
    for (int c = 0; c < 4; c++) {                // B: 4 calls/wave
      const int row = (w * 4 + c) * 4 + l16;
      const int lch = l15 ^ (row & 7);
      async_cp16(&Bs[(w * 4 + c) * 512],
                 WoT + (size_t)(bn + row) * 9216 + k0 + lch * 8);
    }
    __syncthreads();

    #pragma unroll
    for (int s = 0; s < 4; s++) {
      const int pc = ((s * 4 + q) ^ (m16 & 7)) * 8;
      short8 af[2], bfr[4];
      #pragma unroll
      for (int mt = 0; mt < 2; mt++)
        af[mt] = *reinterpret_cast<const short8*>(
            &As[(w * 32 + mt * 16 + m16) * 128 + pc]);
      #pragma unroll
      for (int nt = 0; nt < 4; nt++)
        bfr[nt] = *reinterpret_cast<const short8*>(
            &Bs[(nt * 16 + m16) * 128 + pc]);
      #pragma unroll
      for (int mt = 0; mt < 2; mt++)
        #pragma unroll
        for (int nt = 0; nt < 4; nt++)
          acc[mt][nt] = __builtin_amdgcn_mfma_f32_16x16x32_bf16(
              af[mt], bfr[nt], acc[mt][nt], 0, 0, 0);
    }
  }

  #pragma unroll
  for (int mt = 0; mt < 2; mt++)
    #pragma unroll
    for (int nt = 0; nt < 4; nt++)
      #pragma unroll
      for (int r = 0; r < 4; r++) {
        const int row = bm + w * 32 + mt * 16 + q * 4 + r;
        const int col = bn + nt * 16 + m16;
        atomicAdd(&out[(size_t)row * 512 + col], acc[mt][nt][r]);
      }
}

extern "C" void kernel_launch(void* const* d_in, const int* in_sizes, int n_in,
                              void* d_out, int out_size, void* d_ws, size_t ws_size,
                              hipStream_t stream) {
  const float* queries = (const float*)d_in[0];
  const float* keys    = (const float*)d_in[1];
  const float* values  = (const float*)d_in[2];
  // d_in[3] = attn_mask (unused by reference)
  const float* Wq   = (const float*)d_in[4];
  const float* bq   = (const float*)d_in[5];
  const float* Wk   = (const float*)d_in[6];
  const float* bk   = (const float*)d_in[7];
  const float* Wv   = (const float*)d_in[8];
  const float* bv   = (const float*)d_in[9];
  const float* core = (const float*)d_in[10];
  const float* Wo   = (const float*)d_in[11];
  const float* bo   = (const float*)d_in[12];
  float* out = (float*)d_out;

  char* ws = (char*)d_ws;
  bf16* AQb = (bf16*)(ws);                   // 3.15 MB (3072*512) = core*q/8
  bf16* KPb = (bf16*)(ws + 3145728);         // 3.15 MB
  bf16* VPb = (bf16*)(ws + 6291456);         // 3.15 MB
  bf16* WTq = (bf16*)(ws + 9437184);         // 0.52 MB (512*512)
  bf16* WTk = (bf16*)(ws + 9961472);         // 0.52 MB
  bf16* WTv = (bf16*)(ws + 10485760);        // 0.52 MB
  bf16* WoT = (bf16*)(ws + 11010048);        // 9.44 MB (512*9216)
  bf16* FULL = (bf16*)(ws + 20447232);       // 56.62 MB (3072*9216)
  // Xb* overlay the FULL region: proj reads them before stage_b writes FULL.
  bf16* Xbq = FULL;
  bf16* Xbk = FULL + 1572864;
  bf16* Xbv = FULL + 3145728;

  const dim3 blk(256);

  prep<<<dim3(8064), blk, 0, stream>>>(
      Wo, Wq, Wk, Wv, queries, keys, values, bo,
      WoT, WTq, WTk, WTv, Xbq, Xbk, Xbv, out);

  proj_mfma<<<dim3(24, 8, 3), blk, 0, stream>>>(
      Xbq, Xbk, Xbv, WTq, WTk, WTv, bq, bk, bv, core, AQb, KPb, VPb);

  stage_b_mfma<<<dim3(48, 32), blk, 0, stream>>>(AQb, KPb, VPb, FULL);

  stage_c_mfma<<<dim3(24, 8, 4), blk, 0, stream>>>(FULL, WoT, out);
}